// Round 1
// baseline (149.310 us; speedup 1.0000x reference)
//
#include <hip/hip_runtime.h>

// Problem constants (fixed by setup_inputs)
constexpr int B   = 256;
constexpr int IN  = 256;
constexpr int OUT = 512;
constexpr double EPSD = 1e-7;

// ---------------------------------------------------------------------------
// Kernel 1: setup
//   blocks 0..31 : RXD[b,i] = 1/(x[b,i]+eps)  (f64), 8 b-rows per block
//   block 32     : COL[i] = sum_b x[b,i]      (f64)
//   block 33     : WARG[o] = argmax_i w[i,o]  (first-max semantics)
// ---------------------------------------------------------------------------
__global__ void k_setup(const float* __restrict__ x, const float* __restrict__ w,
                        double* __restrict__ rxd, double* __restrict__ col,
                        int* __restrict__ warg) {
    const int tid = threadIdx.x;   // 0..255
    const int blk = blockIdx.x;
    if (blk < 32) {
        const int b0 = blk * 8;
        #pragma unroll
        for (int k = 0; k < 8; ++k) {
            const int b = b0 + k;
            double xv = (double)x[b * IN + tid];
            rxd[b * IN + tid] = 1.0 / (xv + EPSD);
        }
    } else if (blk == 32) {
        double s = 0.0;
        for (int b = 0; b < B; ++b) s += (double)x[b * IN + tid];
        col[tid] = s;
    } else {
        // per-column argmax of w, 2 columns per thread
        for (int o = tid; o < OUT; o += 256) {
            float best = -1.0f; int bi = 0;
            for (int i = 0; i < IN; ++i) {
                float v = w[i * OUT + o];
                if (v > best) { best = v; bi = i; }   // strict > => first max
            }
            warg[o] = bi;
        }
    }
}

// ---------------------------------------------------------------------------
// Kernel 2: REL[i,o] = (sum_b min(t[b,o]*RXD[b,i], 1)) / COL[i]   (f64)
//   grid = OUT blocks (one per o), 256 threads (one per i)
//   t-column staged in LDS (broadcast reads), RXD loads coalesced across i
// ---------------------------------------------------------------------------
__global__ void k_rel(const float* __restrict__ t, const double* __restrict__ rxd,
                      const double* __restrict__ col, double* __restrict__ rel) {
    const int i = threadIdx.x;   // 0..255
    const int o = blockIdx.x;    // 0..511
    __shared__ double tcol[B];
    tcol[i] = (double)t[i * OUT + o];
    __syncthreads();
    double acc = 0.0;
    #pragma unroll 4
    for (int b = 0; b < B; ++b) {
        double q = tcol[b] * rxd[b * IN + i];
        acc += fmin(q, 1.0);
    }
    rel[i * OUT + o] = acc / col[i];
}

// ---------------------------------------------------------------------------
// Kernel 3: outputs
//   grid = B blocks (one per b), 256 threads; each thread handles o = tid, tid+256
//   out0[b,o] = x[b,ia]*w[ia,o],  ia = argmax_i x[b,i]*REL[i,o]  (f64 scores)
//   out1[b,o] = x[b,iw]*w[iw,o],  iw = t[b,o]>0 ? WARG[o] : 0
// ---------------------------------------------------------------------------
__global__ void k_out(const float* __restrict__ x, const float* __restrict__ w,
                      const float* __restrict__ t, const double* __restrict__ rel,
                      const int* __restrict__ warg, float* __restrict__ out) {
    const int b   = blockIdx.x;
    const int tid = threadIdx.x;
    __shared__ double xrow[IN];
    xrow[tid] = (double)x[b * IN + tid];
    __syncthreads();

    float* __restrict__ out0 = out;
    float* __restrict__ out1 = out + (size_t)B * OUT;

    for (int o = tid; o < OUT; o += 256) {
        double best = -1.0; int bi = 0;
        #pragma unroll 4
        for (int i = 0; i < IN; ++i) {
            double s = xrow[i] * rel[i * OUT + o];
            if (s > best) { best = s; bi = i; }      // strict > => first max
        }
        out0[b * OUT + o] = x[b * IN + bi] * w[bi * OUT + o];

        float tv = t[b * OUT + o];
        int iw = (tv > 0.0f) ? warg[o] : 0;
        out1[b * OUT + o] = x[b * IN + iw] * w[iw * OUT + o];
    }
}

// ---------------------------------------------------------------------------
extern "C" void kernel_launch(void* const* d_in, const int* in_sizes, int n_in,
                              void* d_out, int out_size, void* d_ws, size_t ws_size,
                              hipStream_t stream) {
    const float* x = (const float*)d_in[0];   // (B, IN)
    const float* w = (const float*)d_in[1];   // (IN, OUT)
    const float* t = (const float*)d_in[2];   // (B, OUT)
    float* out = (float*)d_out;               // 2 * B * OUT floats

    double* dws = (double*)d_ws;
    double* REL = dws;                              // IN*OUT   = 131072 doubles
    double* RXD = dws + (size_t)IN * OUT;           // B*IN     =  65536 doubles
    double* COL = RXD + (size_t)B * IN;             // IN       =    256 doubles
    int*    WARG = (int*)(COL + IN);                // OUT ints

    k_setup<<<34, 256, 0, stream>>>(x, w, RXD, COL, WARG);
    k_rel<<<OUT, 256, 0, stream>>>(t, RXD, COL, REL);
    k_out<<<B, 256, 0, stream>>>(x, w, t, REL, WARG, out);
}

// Round 2
// 109.920 us; speedup vs baseline: 1.3583x; 1.3583x over previous
//
#include <hip/hip_runtime.h>

// Problem constants (fixed by setup_inputs)
constexpr int B   = 256;
constexpr int IN  = 256;
constexpr int OUT = 512;
constexpr double EPSD = 1e-7;

// ---------------------------------------------------------------------------
// Workspace layout (all built fresh every launch):
//   RELT [OUT][IN] f64  (1 MB)   rel_x transposed, o-major
//   RXD  [B][IN]   f64  (512 KB) 1/(x+eps)
//   RCOL [IN]      f64  (2 KB)   1/colsum(x)
//   XT   [IN][B]   f32  (256 KB) x transposed, i-major
//   WARG [OUT]     int  (2 KB)   argmax_i w[i][o] (first-max)
// ---------------------------------------------------------------------------

// Kernel 1: setup (42 tiny blocks)
__global__ void k_setup(const float* __restrict__ x, const float* __restrict__ w,
                        double* __restrict__ rxd, double* __restrict__ rcol,
                        float* __restrict__ xt, int* __restrict__ warg) {
    const int tid = threadIdx.x;   // 0..255
    const int blk = blockIdx.x;
    if (blk < 32) {                          // RXD rows, 8 b-rows per block
        const int b0 = blk * 8;
        #pragma unroll
        for (int k = 0; k < 8; ++k) {
            const int b = b0 + k;
            rxd[b * IN + tid] = 1.0 / ((double)x[b * IN + tid] + EPSD);
        }
    } else if (blk == 32) {                  // 1/colsum
        double s = 0.0;
        for (int b = 0; b < B; ++b) s += (double)x[b * IN + tid];
        rcol[tid] = 1.0 / s;
    } else if (blk == 33) {                  // per-column argmax of w (first-max)
        for (int o = tid; o < OUT; o += 256) {
            float best = -1.0f; int bi = 0;
            for (int i = 0; i < IN; ++i) {
                float v = w[i * OUT + o];
                if (v > best) { best = v; bi = i; }
            }
            warg[o] = bi;
        }
    } else {                                 // blocks 34..41: XT transpose, 32 i-rows each
        const int i0 = (blk - 34) * 32;
        for (int k = 0; k < 32; ++k) {
            const int i = i0 + k;
            xt[i * B + tid] = x[tid * IN + i];   // uncoalesced read, coalesced write
        }
    }
}

// ---------------------------------------------------------------------------
// Kernel 2: RELT[o][i] = (sum_b min(t[b,o]*RXD[b,i], 1)) * RCOL[i]
//   grid 256 blocks x 512 threads; block covers o = 2*blk + (tid>>8), i = tid&255
//   4 independent f64 accumulator chains; both o-halves hit same rxd lines (L1)
// ---------------------------------------------------------------------------
__global__ __launch_bounds__(512) void k_rel(const float* __restrict__ t,
                      const double* __restrict__ rxd, const double* __restrict__ rcol,
                      double* __restrict__ relt) {
    const int tid  = threadIdx.x;
    const int half = tid >> 8;          // 0 or 1
    const int i    = tid & 255;
    const int o    = blockIdx.x * 2 + half;
    __shared__ double tc[2][B];
    tc[half][i] = (double)t[i * OUT + o];
    __syncthreads();
    const double* __restrict__ rx  = rxd + i;
    const double* __restrict__ tcc = tc[half];
    double a0 = 0.0, a1 = 0.0, a2 = 0.0, a3 = 0.0;
    #pragma unroll 2
    for (int b = 0; b < B; b += 4) {
        a0 += fmin(tcc[b + 0] * rx[(b + 0) * IN], 1.0);
        a1 += fmin(tcc[b + 1] * rx[(b + 1) * IN], 1.0);
        a2 += fmin(tcc[b + 2] * rx[(b + 2) * IN], 1.0);
        a3 += fmin(tcc[b + 3] * rx[(b + 3) * IN], 1.0);
    }
    relt[o * IN + i] = ((a0 + a1) + (a2 + a3)) * rcol[i];
}

// ---------------------------------------------------------------------------
// Kernel 3: outputs
//   grid 256 blocks x 512 threads; block covers o = 2*blk + (tid>>8), b = tid&255
//   argmax via index-embedded f64 max chains:
//     score s = (f64)x[b,i] * rel[i,o] > 0; low 8 mantissa bits := 255-i
//     => v_max_f64 chain gives argmax with first-occurrence tie semantics.
//   Perturbation 2^-44 relative << score margins (R1 matched np exactly).
// ---------------------------------------------------------------------------
__global__ __launch_bounds__(512) void k_out(const float* __restrict__ xt,
                      const float* __restrict__ w, const float* __restrict__ t,
                      const double* __restrict__ relt, const int* __restrict__ warg,
                      float* __restrict__ out) {
    const int tid  = threadIdx.x;
    const int half = tid >> 8;
    const int b    = tid & 255;
    const int o    = blockIdx.x * 2 + half;
    __shared__ double rc[2][IN];
    rc[half][b] = relt[o * IN + b];     // coalesced stage of rel column
    __syncthreads();
    const double* __restrict__ rcc = rc[half];

    double m0 = -1.0, m1 = -1.0, m2 = -1.0, m3 = -1.0;
    #pragma unroll 2
    for (int i = 0; i < IN; i += 4) {
        double s0 = (double)xt[(i + 0) * B + b] * rcc[i + 0];
        double s1 = (double)xt[(i + 1) * B + b] * rcc[i + 1];
        double s2 = (double)xt[(i + 2) * B + b] * rcc[i + 2];
        double s3 = (double)xt[(i + 3) * B + b] * rcc[i + 3];
        long long u0 = (__double_as_longlong(s0) & ~0xFFll) | (long long)(255 - (i + 0));
        long long u1 = (__double_as_longlong(s1) & ~0xFFll) | (long long)(255 - (i + 1));
        long long u2 = (__double_as_longlong(s2) & ~0xFFll) | (long long)(255 - (i + 2));
        long long u3 = (__double_as_longlong(s3) & ~0xFFll) | (long long)(255 - (i + 3));
        m0 = fmax(m0, __longlong_as_double(u0));
        m1 = fmax(m1, __longlong_as_double(u1));
        m2 = fmax(m2, __longlong_as_double(u2));
        m3 = fmax(m3, __longlong_as_double(u3));
    }
    double m = fmax(fmax(m0, m1), fmax(m2, m3));
    const int ia = 255 - (int)(__double_as_longlong(m) & 0xFF);

    float* __restrict__ out0 = out;
    float* __restrict__ out1 = out + (size_t)B * OUT;
    out0[b * OUT + o] = xt[ia * B + b] * w[ia * OUT + o];   // f32 mul, matches ref

    const float tv = t[b * OUT + o];
    const int iw = (tv > 0.0f) ? warg[o] : 0;
    out1[b * OUT + o] = xt[iw * B + b] * w[iw * OUT + o];
}

// ---------------------------------------------------------------------------
extern "C" void kernel_launch(void* const* d_in, const int* in_sizes, int n_in,
                              void* d_out, int out_size, void* d_ws, size_t ws_size,
                              hipStream_t stream) {
    const float* x = (const float*)d_in[0];   // (B, IN)
    const float* w = (const float*)d_in[1];   // (IN, OUT)
    const float* t = (const float*)d_in[2];   // (B, OUT)
    float* out = (float*)d_out;               // 2 * B * OUT floats

    double* dws = (double*)d_ws;
    double* RELT = dws;                              // OUT*IN doubles (1 MB)
    double* RXD  = RELT + (size_t)OUT * IN;          // B*IN doubles  (512 KB)
    double* RCOL = RXD + (size_t)B * IN;             // IN doubles
    float*  XT   = (float*)(RCOL + IN);              // IN*B floats   (256 KB)
    int*    WARG = (int*)(XT + (size_t)IN * B);      // OUT ints

    k_setup<<<42, 256, 0, stream>>>(x, w, RXD, RCOL, XT, WARG);
    k_rel<<<OUT / 2, 512, 0, stream>>>(t, RXD, RCOL, RELT);
    k_out<<<OUT / 2, 512, 0, stream>>>(XT, w, t, RELT, WARG, out);
}

// Round 3
// 91.558 us; speedup vs baseline: 1.6308x; 1.2006x over previous
//
#include <hip/hip_runtime.h>

// Problem constants (fixed by setup_inputs)
constexpr int B   = 256;
constexpr int IN  = 256;
constexpr int OUT = 512;
constexpr double EPSD = 1e-7;

// ---------------------------------------------------------------------------
// Workspace layout (rebuilt every launch):
//   RXD  [B][IN]  f64  (512 KB)  1/(x+eps)
//   PART [8][IN]  f64  (16 KB)   partial colsums of x (32 b-rows each)
//   XT   [IN][B]  f32  (256 KB)  x transposed
// RELT no longer exists: rel lives in LDS of the merged kernel.
// ---------------------------------------------------------------------------

// Kernel 1: setup (48 blocks x 256 threads, all phases parallel-friendly)
__global__ __launch_bounds__(256) void k_setup(const float* __restrict__ x,
        double* __restrict__ rxd, double* __restrict__ part, float* __restrict__ xt) {
    const int tid = threadIdx.x;
    const int blk = blockIdx.x;
    if (blk < 32) {                          // RXD: 8 b-rows per block, coalesced
        const int b0 = blk * 8;
        #pragma unroll
        for (int k = 0; k < 8; ++k)
            rxd[(b0 + k) * IN + tid] = 1.0 / ((double)x[(b0 + k) * IN + tid] + EPSD);
    } else if (blk < 40) {                   // partial colsums: 32 b-rows per block
        const int j = blk - 32, b0 = j * 32;
        double s0 = 0, s1 = 0, s2 = 0, s3 = 0;
        #pragma unroll
        for (int k = 0; k < 32; k += 4) {
            s0 += (double)x[(b0 + k + 0) * IN + tid];
            s1 += (double)x[(b0 + k + 1) * IN + tid];
            s2 += (double)x[(b0 + k + 2) * IN + tid];
            s3 += (double)x[(b0 + k + 3) * IN + tid];
        }
        part[j * IN + tid] = (s0 + s1) + (s2 + s3);
    } else {                                 // XT: 32 i-rows per block, coalesced writes
        const int i0 = (blk - 40) * 32;
        for (int k = 0; k < 32; ++k)
            xt[(i0 + k) * B + tid] = x[tid * IN + (i0 + k)];
    }
}

// ---------------------------------------------------------------------------
// Kernel 2 (merged): per block, o-pair = (2*blk, 2*blk+1); 512 threads.
//   Phase W: per-half argmax_i w[i,o] via 64-bit-key shfl reduce (first-max).
//   Phase 1: rel column for (i = tid&255, o = half) -> LDS rc[].
//   Phase 2: out0 via index-embedded f64 fmax argmax; out1 via warg.
// ---------------------------------------------------------------------------
__global__ __launch_bounds__(512, 2) void k_main(const float* __restrict__ w,
        const float* __restrict__ t, const double* __restrict__ rxd,
        const double* __restrict__ part, const float* __restrict__ xt,
        float* __restrict__ out) {
    const int tid  = threadIdx.x;
    const int half = tid >> 8;          // 0 or 1
    const int j    = tid & 255;         // i in phase 1, b in phase 2
    const int o    = blockIdx.x * 2 + half;

    __shared__ double tc[2 * B];                 // staged t columns (f64)
    __shared__ double rc[2 * IN];                // rel columns
    __shared__ unsigned long long swv[8];        // per-wave warg keys

    // --- phase W: argmax_i w[i,o] (w >= 0 so f32 bits are order-preserving) ---
    {
        float wv = w[j * OUT + o];
        unsigned long long key =
            ((unsigned long long)__float_as_uint(wv) << 8) | (unsigned)(255 - j);
        #pragma unroll
        for (int off = 32; off; off >>= 1) {
            unsigned long long v = __shfl_down(key, off);
            key = v > key ? v : key;
        }
        if ((tid & 63) == 0) swv[tid >> 6] = key;
    }

    // --- stage t column; combine colsum partials ---
    tc[half * B + j] = (double)t[j * OUT + o];
    double ps = 0.0;
    #pragma unroll
    for (int k = 0; k < 8; ++k) ps += part[k * IN + j];
    const double rcolv = 1.0 / ps;
    __syncthreads();

    unsigned long long wk = swv[half * 4];
    #pragma unroll
    for (int k = 1; k < 4; ++k) {
        unsigned long long v = swv[half * 4 + k];
        wk = v > wk ? v : wk;
    }
    const int warg_o = 255 - (int)(wk & 0xFFull);

    // --- phase 1: rel[(i=j), o] = sum_b min(t[b,o]*rxd[b,i],1) * rcol[i] ---
    {
        const double* __restrict__ rx  = rxd + j;     // coalesced across i
        const double* __restrict__ tcc = tc + half * B;
        double a0 = 0, a1 = 0, a2 = 0, a3 = 0;
        #pragma unroll 2
        for (int b = 0; b < B; b += 4) {
            a0 += fmin(tcc[b + 0] * rx[(b + 0) * IN], 1.0);
            a1 += fmin(tcc[b + 1] * rx[(b + 1) * IN], 1.0);
            a2 += fmin(tcc[b + 2] * rx[(b + 2) * IN], 1.0);
            a3 += fmin(tcc[b + 3] * rx[(b + 3) * IN], 1.0);
        }
        rc[half * IN + j] = ((a0 + a1) + (a2 + a3)) * rcolv;
    }
    __syncthreads();

    // --- phase 2: outputs for (b=j, o) ---
    const int b = j;
    const double* __restrict__ rcc = rc + half * IN;  // broadcast LDS reads
    double m0 = -1.0, m1 = -1.0, m2 = -1.0, m3 = -1.0;
    #pragma unroll 2
    for (int i = 0; i < IN; i += 4) {
        double s0 = (double)xt[(i + 0) * B + b] * rcc[i + 0];
        double s1 = (double)xt[(i + 1) * B + b] * rcc[i + 1];
        double s2 = (double)xt[(i + 2) * B + b] * rcc[i + 2];
        double s3 = (double)xt[(i + 3) * B + b] * rcc[i + 3];
        long long u0 = (__double_as_longlong(s0) & ~0xFFll) | (long long)(255 - (i + 0));
        long long u1 = (__double_as_longlong(s1) & ~0xFFll) | (long long)(255 - (i + 1));
        long long u2 = (__double_as_longlong(s2) & ~0xFFll) | (long long)(255 - (i + 2));
        long long u3 = (__double_as_longlong(s3) & ~0xFFll) | (long long)(255 - (i + 3));
        m0 = fmax(m0, __longlong_as_double(u0));
        m1 = fmax(m1, __longlong_as_double(u1));
        m2 = fmax(m2, __longlong_as_double(u2));
        m3 = fmax(m3, __longlong_as_double(u3));
    }
    double m = fmax(fmax(m0, m1), fmax(m2, m3));
    const int ia = 255 - (int)(__double_as_longlong(m) & 0xFF);

    float* __restrict__ out0 = out;
    float* __restrict__ out1 = out + (size_t)B * OUT;
    out0[b * OUT + o] = xt[ia * B + b] * w[ia * OUT + o];   // f32 mul, matches ref

    const int iw = (tc[half * B + b] > 0.0) ? warg_o : 0;   // reuse staged t
    out1[b * OUT + o] = xt[iw * B + b] * w[iw * OUT + o];
}

// ---------------------------------------------------------------------------
extern "C" void kernel_launch(void* const* d_in, const int* in_sizes, int n_in,
                              void* d_out, int out_size, void* d_ws, size_t ws_size,
                              hipStream_t stream) {
    const float* x = (const float*)d_in[0];   // (B, IN)
    const float* w = (const float*)d_in[1];   // (IN, OUT)
    const float* t = (const float*)d_in[2];   // (B, OUT)
    float* out = (float*)d_out;               // 2 * B * OUT floats

    double* dws  = (double*)d_ws;
    double* RXD  = dws;                             // B*IN doubles (512 KB)
    double* PART = RXD + (size_t)B * IN;            // 8*IN doubles (16 KB)
    float*  XT   = (float*)(PART + 8 * IN);         // IN*B floats  (256 KB)

    k_setup<<<48, 256, 0, stream>>>(x, RXD, PART, XT);
    k_main<<<OUT / 2, 512, 0, stream>>>(w, t, RXD, PART, XT, out);
}

// Round 4
// 83.641 us; speedup vs baseline: 1.7851x; 1.0947x over previous
//
#include <hip/hip_runtime.h>

// Problem constants (fixed by setup_inputs)
constexpr int B   = 256;
constexpr int IN  = 256;
constexpr int OUT = 512;
constexpr double EPSD = 1e-7;

typedef unsigned long long ull;

// ---------------------------------------------------------------------------
// Workspace layout (rebuilt every launch):
//   RXD  [B][IN]  f64  (512 KB)  1/(x+eps)
//   PART [8][IN]  f64  (16 KB)   partial colsums of x
//   XT   [IN][B]  f32  (256 KB)  x transposed
// ---------------------------------------------------------------------------

__global__ __launch_bounds__(256) void k_setup(const float* __restrict__ x,
        double* __restrict__ rxd, double* __restrict__ part, float* __restrict__ xt) {
    const int tid = threadIdx.x;
    const int blk = blockIdx.x;
    if (blk < 32) {                          // RXD: 8 b-rows per block, coalesced
        const int b0 = blk * 8;
        #pragma unroll
        for (int k = 0; k < 8; ++k)
            rxd[(b0 + k) * IN + tid] = 1.0 / ((double)x[(b0 + k) * IN + tid] + EPSD);
    } else if (blk < 40) {                   // partial colsums: 32 b-rows per block
        const int j = blk - 32, b0 = j * 32;
        double s0 = 0, s1 = 0, s2 = 0, s3 = 0;
        #pragma unroll
        for (int k = 0; k < 32; k += 4) {
            s0 += (double)x[(b0 + k + 0) * IN + tid];
            s1 += (double)x[(b0 + k + 1) * IN + tid];
            s2 += (double)x[(b0 + k + 2) * IN + tid];
            s3 += (double)x[(b0 + k + 3) * IN + tid];
        }
        part[j * IN + tid] = (s0 + s1) + (s2 + s3);
    } else {                                 // XT: 32 i-rows per block
        const int i0 = (blk - 40) * 32;
        for (int k = 0; k < 32; ++k)
            xt[(i0 + k) * B + tid] = x[tid * IN + (i0 + k)];
    }
}

// ---------------------------------------------------------------------------
// Merged main kernel: block = o-pair (2*blk, 2*blk+1), 512 threads.
//   Phase W: argmax_i w[i,o] via 64-bit-key shfl reduce (first-max).
//   Phase 1: rel column -> thread owns (i-pair, b-half); double2 loads;
//            partials combined in LDS.
//   Phase 2: out0 argmax -> thread owns (b-pair, i-half); float2 loads;
//            index-embedded f64 max keys combined in LDS; out1 via warg.
// ---------------------------------------------------------------------------
__global__ __launch_bounds__(512, 2) void k_main(const float* __restrict__ w,
        const float* __restrict__ t, const double* __restrict__ rxd,
        const double* __restrict__ part, const float* __restrict__ xt,
        float* __restrict__ out) {
    const int tid  = threadIdx.x;
    const int half = tid >> 8;          // which o of the pair
    const int j    = tid & 255;
    const int o    = blockIdx.x * 2 + half;

    __shared__ double tc[2][B];          // staged t columns (f64)        4 KB
    __shared__ double rp[2][2][IN];      // rel partials [half][bh][i]    8 KB
    __shared__ double rc[2][IN];         // rel columns                   4 KB
    __shared__ ull    keys[2][2][B];     // argmax keys [half][ih][b]     8 KB
    __shared__ ull    swv[8];            // per-wave warg keys

    // --- phase W: argmax_i w[i,o]  (w>=0 so f32 bits order-preserving) ---
    {
        float wv = w[j * OUT + o];
        ull key = ((ull)__float_as_uint(wv) << 8) | (unsigned)(255 - j);
        #pragma unroll
        for (int off = 32; off; off >>= 1) {
            ull v = __shfl_down(key, off);
            key = v > key ? v : key;
        }
        if ((tid & 63) == 0) swv[tid >> 6] = key;
    }

    // --- stage t column; per-thread 1/colsum for i=j ---
    tc[half][j] = (double)t[j * OUT + o];
    double ps = 0.0;
    #pragma unroll
    for (int k = 0; k < 8; ++k) ps += part[k * IN + j];
    const double rcolv = 1.0 / ps;
    __syncthreads();

    ull wk = swv[half * 4];
    #pragma unroll
    for (int k = 1; k < 4; ++k) { ull v = swv[half * 4 + k]; wk = v > wk ? v : wk; }
    const int warg_o = 255 - (int)(wk & 0xFFull);

    // --- phase 1: partial rel sums; thread = (i-pair, b-half) ---
    {
        const int i0 = (j & 127) * 2;
        const int bh = j >> 7;
        const double* __restrict__ tcc  = tc[half] + bh * 128;
        const double* __restrict__ base = rxd + (size_t)(bh * 128) * IN + i0;
        double a0 = 0, a1 = 0, a2 = 0, a3 = 0;
        #pragma unroll 8
        for (int k = 0; k < 128; k += 2) {
            double2 r0 = *(const double2*)(base + (size_t)k * IN);
            double2 r1 = *(const double2*)(base + (size_t)(k + 1) * IN);
            double t0 = tcc[k], t1 = tcc[k + 1];
            a0 += fmin(t0 * r0.x, 1.0);
            a1 += fmin(t0 * r0.y, 1.0);
            a2 += fmin(t1 * r1.x, 1.0);
            a3 += fmin(t1 * r1.y, 1.0);
        }
        rp[half][bh][i0]     = a0 + a2;
        rp[half][bh][i0 + 1] = a1 + a3;
    }
    __syncthreads();
    rc[half][j] = (rp[half][0][j] + rp[half][1][j]) * rcolv;   // i = j
    __syncthreads();

    // --- phase 2: argmax_i x[b,i]*rel[i,o]; thread = (b-pair, i-half) ---
    {
        const int b0 = (j & 127) * 2;
        const int ih = j >> 7;
        const double* __restrict__ rcc = rc[half];
        double mA0 = -1.0, mA1 = -1.0, mB0 = -1.0, mB1 = -1.0;  // chains: bA=b0, bB=b0+1
        #pragma unroll 8
        for (int i = ih * 128; i < ih * 128 + 128; i += 2) {
            float2 x0 = *(const float2*)&xt[(size_t)i * B + b0];
            float2 x1 = *(const float2*)&xt[(size_t)(i + 1) * B + b0];
            double s00 = (double)x0.x * rcc[i];
            double s01 = (double)x0.y * rcc[i];
            double s10 = (double)x1.x * rcc[i + 1];
            double s11 = (double)x1.y * rcc[i + 1];
            long long u00 = (__double_as_longlong(s00) & ~0xFFll) | (long long)(255 - i);
            long long u01 = (__double_as_longlong(s01) & ~0xFFll) | (long long)(255 - i);
            long long u10 = (__double_as_longlong(s10) & ~0xFFll) | (long long)(255 - (i + 1));
            long long u11 = (__double_as_longlong(s11) & ~0xFFll) | (long long)(255 - (i + 1));
            mA0 = fmax(mA0, __longlong_as_double(u00));
            mB0 = fmax(mB0, __longlong_as_double(u01));
            mA1 = fmax(mA1, __longlong_as_double(u10));
            mB1 = fmax(mB1, __longlong_as_double(u11));
        }
        keys[half][ih][b0]     = (ull)__double_as_longlong(fmax(mA0, mA1));
        keys[half][ih][b0 + 1] = (ull)__double_as_longlong(fmax(mB0, mB1));
    }
    __syncthreads();

    // --- finish: thread handles b = b-pair-base + ih ---
    {
        const int b = (j & 127) * 2 + (j >> 7);
        ull k0 = keys[half][0][b], k1 = keys[half][1][b];
        ull mk = k0 > k1 ? k0 : k1;          // positive doubles: bit order = value order
        const int ia = 255 - (int)(mk & 0xFFull);

        float* __restrict__ out0 = out;
        float* __restrict__ out1 = out + (size_t)B * OUT;
        out0[b * OUT + o] = xt[(size_t)ia * B + b] * w[ia * OUT + o];

        const int iw = (tc[half][b] > 0.0) ? warg_o : 0;
        out1[b * OUT + o] = xt[(size_t)iw * B + b] * w[iw * OUT + o];
    }
}

// ---------------------------------------------------------------------------
extern "C" void kernel_launch(void* const* d_in, const int* in_sizes, int n_in,
                              void* d_out, int out_size, void* d_ws, size_t ws_size,
                              hipStream_t stream) {
    const float* x = (const float*)d_in[0];   // (B, IN)
    const float* w = (const float*)d_in[1];   // (IN, OUT)
    const float* t = (const float*)d_in[2];   // (B, OUT)
    float* out = (float*)d_out;               // 2 * B * OUT floats

    double* dws  = (double*)d_ws;
    double* RXD  = dws;                             // B*IN doubles (512 KB)
    double* PART = RXD + (size_t)B * IN;            // 8*IN doubles (16 KB)
    float*  XT   = (float*)(PART + 8 * IN);         // IN*B floats  (256 KB)

    k_setup<<<48, 256, 0, stream>>>(x, RXD, PART, XT);
    k_main<<<OUT / 2, 512, 0, stream>>>(w, t, RXD, PART, XT, out);
}

// Round 5
// 82.763 us; speedup vs baseline: 1.8041x; 1.0106x over previous
//
#include <hip/hip_runtime.h>

// Problem constants (fixed by setup_inputs)
constexpr int B   = 256;
constexpr int IN  = 256;
constexpr int OUT = 512;
constexpr double EPSD = 1e-7;

typedef unsigned long long ull;

// ---------------------------------------------------------------------------
// Workspace:
//   RXD  [B][IN]  f64  (512 KB)  1/(x+eps)
//   PART [8][IN]  f64  (16 KB)   partial colsums of x
//   XT   [IN][B]  f32  (256 KB)  x transposed
// ---------------------------------------------------------------------------

__global__ __launch_bounds__(256) void k_setup(const float* __restrict__ x,
        double* __restrict__ rxd, double* __restrict__ part, float* __restrict__ xt) {
    const int tid = threadIdx.x;
    const int blk = blockIdx.x;
    if (blk < 32) {                          // RXD: 8 b-rows per block, coalesced
        const int b0 = blk * 8;
        #pragma unroll
        for (int k = 0; k < 8; ++k)
            rxd[(b0 + k) * IN + tid] = 1.0 / ((double)x[(b0 + k) * IN + tid] + EPSD);
    } else if (blk < 40) {                   // partial colsums: 32 b-rows per block
        const int j = blk - 32, b0 = j * 32;
        double s0 = 0, s1 = 0, s2 = 0, s3 = 0;
        #pragma unroll
        for (int k = 0; k < 32; k += 4) {
            s0 += (double)x[(b0 + k + 0) * IN + tid];
            s1 += (double)x[(b0 + k + 1) * IN + tid];
            s2 += (double)x[(b0 + k + 2) * IN + tid];
            s3 += (double)x[(b0 + k + 3) * IN + tid];
        }
        part[j * IN + tid] = (s0 + s1) + (s2 + s3);
    } else {                                 // XT: LDS-tiled 64x64 transpose, 16 tiles
        __shared__ float tile[64][65];
        const int tl  = blk - 40;            // 0..15
        const int tr0 = (tl >> 2) * 64;      // b-tile origin (rows of x)
        const int tc0 = (tl & 3) * 64;       // i-tile origin (cols of x)
        const int c   = tid & 63;
        const int r4  = tid >> 6;            // 0..3
        #pragma unroll
        for (int k = 0; k < 16; ++k) {
            const int r = r4 + k * 4;
            tile[r][c] = x[(tr0 + r) * IN + tc0 + c];     // coalesced read
        }
        __syncthreads();
        #pragma unroll
        for (int k = 0; k < 16; ++k) {
            const int r = r4 + k * 4;                      // i-local
            xt[(size_t)(tc0 + r) * B + tr0 + c] = tile[c][r];  // coalesced write
        }
    }
}

// ---------------------------------------------------------------------------
// Merged main kernel: one block per o, 512 threads, 2 blocks/CU.
//   Phase W: argmax_i w[i,o] (first-max) via 64-bit-key shfl reduce (waves 0-3).
//   Phase 1: rel partials; thread = (i-pair, b-quarter); double2 rxd loads.
//   Phase 2: out0 argmax; thread = (b-pair, i-quarter); float2 xt loads;
//            index-embedded f64 max keys; 4-way LDS combine.
// ---------------------------------------------------------------------------
__global__ __launch_bounds__(512, 4) void k_main(const float* __restrict__ w,
        const float* __restrict__ t, const double* __restrict__ rxd,
        const double* __restrict__ part, const float* __restrict__ xt,
        float* __restrict__ out) {
    const int tid = threadIdx.x;
    const int j   = tid & 255;
    const int o   = blockIdx.x;

    __shared__ double tc[B];          // staged t column (f64)      2 KB
    __shared__ double rcs[IN];        // 1/colsum per i             2 KB
    __shared__ double rp[4][IN];      // rel partials [bq][i]       8 KB
    __shared__ double rc[IN];         // rel column                 2 KB
    __shared__ ull    keys[4][B];     // argmax keys [iq][b]        8 KB
    __shared__ ull    swv[4];         // per-wave warg keys

    int warg_o = 0;
    if (tid < 256) {
        // stage t column + per-i reciprocal colsum
        tc[j] = (double)t[j * OUT + o];
        double ps = 0.0;
        #pragma unroll
        for (int k = 0; k < 8; ++k) ps += part[k * IN + j];
        rcs[j] = 1.0 / ps;
        // w-column argmax (w>=0 so f32 bits are order-preserving)
        float wv = w[j * OUT + o];
        ull key = ((ull)__float_as_uint(wv) << 8) | (unsigned)(255 - j);
        #pragma unroll
        for (int off = 32; off; off >>= 1) {
            ull v = __shfl_down(key, off);
            key = v > key ? v : key;
        }
        if ((tid & 63) == 0) swv[tid >> 6] = key;
    }
    __syncthreads();
    if (tid < 256) {
        ull wk = swv[0];
        #pragma unroll
        for (int k = 1; k < 4; ++k) { ull v = swv[k]; wk = v > wk ? v : wk; }
        warg_o = 255 - (int)(wk & 0xFFull);
    }

    // --- phase 1: rel partials; thread = (i-pair, b-quarter of 64) ---
    {
        const int i0 = (tid & 127) * 2;
        const int bq = tid >> 7;                    // 0..3
        const double* __restrict__ tcc  = tc + bq * 64;
        const double* __restrict__ base = rxd + (size_t)(bq * 64) * IN + i0;
        double a0 = 0, a1 = 0, a2 = 0, a3 = 0;
        #pragma unroll 8
        for (int k = 0; k < 64; k += 2) {
            double2 r0 = *(const double2*)(base + (size_t)k * IN);
            double2 r1 = *(const double2*)(base + (size_t)(k + 1) * IN);
            double t0 = tcc[k], t1 = tcc[k + 1];
            a0 += fmin(t0 * r0.x, 1.0);
            a1 += fmin(t0 * r0.y, 1.0);
            a2 += fmin(t1 * r1.x, 1.0);
            a3 += fmin(t1 * r1.y, 1.0);
        }
        rp[bq][i0]     = a0 + a2;
        rp[bq][i0 + 1] = a1 + a3;
    }
    __syncthreads();
    if (tid < 256)
        rc[j] = (((rp[0][j] + rp[1][j]) + (rp[2][j] + rp[3][j]))) * rcs[j];
    __syncthreads();

    // --- phase 2: argmax_i x[b,i]*rel[i,o]; thread = (b-pair, i-quarter) ---
    {
        const int b0 = (tid & 127) * 2;
        const int iq = tid >> 7;                    // 0..3
        double mA0 = -1.0, mA1 = -1.0, mB0 = -1.0, mB1 = -1.0;
        #pragma unroll 8
        for (int i = iq * 64; i < iq * 64 + 64; i += 2) {
            float2 x0 = *(const float2*)&xt[(size_t)i * B + b0];
            float2 x1 = *(const float2*)&xt[(size_t)(i + 1) * B + b0];
            double s00 = (double)x0.x * rc[i];
            double s01 = (double)x0.y * rc[i];
            double s10 = (double)x1.x * rc[i + 1];
            double s11 = (double)x1.y * rc[i + 1];
            long long u00 = (__double_as_longlong(s00) & ~0xFFll) | (long long)(255 - i);
            long long u01 = (__double_as_longlong(s01) & ~0xFFll) | (long long)(255 - i);
            long long u10 = (__double_as_longlong(s10) & ~0xFFll) | (long long)(255 - (i + 1));
            long long u11 = (__double_as_longlong(s11) & ~0xFFll) | (long long)(255 - (i + 1));
            mA0 = fmax(mA0, __longlong_as_double(u00));
            mB0 = fmax(mB0, __longlong_as_double(u01));
            mA1 = fmax(mA1, __longlong_as_double(u10));
            mB1 = fmax(mB1, __longlong_as_double(u11));
        }
        keys[iq][b0]     = (ull)__double_as_longlong(fmax(mA0, mA1));
        keys[iq][b0 + 1] = (ull)__double_as_longlong(fmax(mB0, mB1));
    }
    __syncthreads();

    // --- finish: thread j handles b = j ---
    if (tid < 256) {
        const int b = j;
        ull mk = keys[0][b];
        #pragma unroll
        for (int k = 1; k < 4; ++k) { ull v = keys[k][b]; mk = v > mk ? v : mk; }
        const int ia = 255 - (int)(mk & 0xFFull);

        float* __restrict__ out0 = out;
        float* __restrict__ out1 = out + (size_t)B * OUT;
        out0[b * OUT + o] = xt[(size_t)ia * B + b] * w[ia * OUT + o];

        const int iw = (tc[b] > 0.0) ? warg_o : 0;
        out1[b * OUT + o] = xt[(size_t)iw * B + b] * w[iw * OUT + o];
    }
}

// ---------------------------------------------------------------------------
extern "C" void kernel_launch(void* const* d_in, const int* in_sizes, int n_in,
                              void* d_out, int out_size, void* d_ws, size_t ws_size,
                              hipStream_t stream) {
    const float* x = (const float*)d_in[0];   // (B, IN)
    const float* w = (const float*)d_in[1];   // (IN, OUT)
    const float* t = (const float*)d_in[2];   // (B, OUT)
    float* out = (float*)d_out;               // 2 * B * OUT floats

    double* dws  = (double*)d_ws;
    double* RXD  = dws;                             // B*IN doubles (512 KB)
    double* PART = RXD + (size_t)B * IN;            // 8*IN doubles (16 KB)
    float*  XT   = (float*)(PART + 8 * IN);         // IN*B floats  (256 KB)

    k_setup<<<56, 256, 0, stream>>>(x, RXD, PART, XT);
    k_main<<<OUT, 512, 0, stream>>>(w, t, RXD, PART, XT, out);
}